// Round 1
// baseline (114.003 us; speedup 1.0000x reference)
//
#include <hip/hip_runtime.h>

// TemporalPyramidPooling: fused overlapping masked window-means,
// (w,stride) = (4,2), (8,4), (16,8), x[8,4096,512] fp32.
// R4: occupancy/latency attack.
//  - f2 lanes (8 B/lane): D split 4-ways -> 4096 single-wave blocks (2x waves).
//  - __launch_bounds__(64,4) + streamed w4 stores (keep only even q4) to cap
//    VGPR <= 128 -> 16 waves/CU reachable.
//  - __builtin_amdgcn_rcpf for the 28 window reciprocals (was 28 IEEE
//    divides ~ 280 wave-uniform VALU instrs).

#define EPS 1e-6f

typedef float f2 __attribute__((ext_vector_type(2)));

constexpr int B = 8, T = 4096, D = 512, D2 = D / 2;  // 256 f2 columns
constexpr int TILE = 32;          // window-start timesteps per block
constexpr int HALO = 8;           // w16 extends 8 past tile
constexpr int NT = TILE + HALO;   // 40 timesteps
constexpr int NP = NT / 2;        // 20 pair sums
constexpr int NTILES = T / TILE;  // 128
constexpr int S4 = 2047, S8 = 1023, S16 = 511;

constexpr size_t OFF0 = 0;                           // avg4  [B,S4,D]
constexpr size_t OFF1 = (size_t)B * S4 * D;          // avg8  [B,S8,D]
constexpr size_t OFF2 = OFF1 + (size_t)B * S8 * D;   // avg16 [B,S16,D]
constexpr size_t OFF3 = OFF2 + (size_t)B * S16 * D;  // mask4 [B,S4]
constexpr size_t OFF4 = OFF3 + (size_t)B * S4;       // mask8 [B,S8]
constexpr size_t OFF5 = OFF4 + (size_t)B * S8;       // mask16[B,S16]

template <bool GUARD>
__device__ __forceinline__ void tile_body(const f2* __restrict__ x2,
                                          const int* __restrict__ mask,
                                          float* __restrict__ out, int b,
                                          int tile, int d2, int lane,
                                          bool write_masks) {
  const int t0 = tile * TILE;

  // ---- wave-uniform mask: scalar loads + in-register float conversion ----
  const int* mp = mask + (size_t)b * T + t0;
  float mf[NT];
#pragma unroll
  for (int i = 0; i < NT; ++i) {
    int m = (!GUARD || (t0 + i) < T) ? mp[i] : 0;
    mf[i] = (m != 0) ? 1.0f : 0.0f;
  }

  // count tree (all wave-uniform)
  float c2[NP];
#pragma unroll
  for (int i = 0; i < NP; ++i) c2[i] = mf[2 * i] + mf[2 * i + 1];
  float c4[19];  // c4[j] = pairs {j,j+1}, j=0..18
#pragma unroll
  for (int j = 0; j < 19; ++j) c4[j] = c2[j] + c2[j + 1];
  float c8[9];  // c8[k] = pairs {2k..2k+3} = c4[2k]+c4[2k+2]
#pragma unroll
  for (int k = 0; k < 9; ++k) c8[k] = c4[2 * k] + c4[2 * k + 2];
  float c16[4];  // c16[l] = pairs {4l..4l+7} = c8[2l]+c8[2l+2]
#pragma unroll
  for (int l = 0; l < 4; ++l) c16[l] = c8[2 * l] + c8[2 * l + 2];

  float i4[16], i8[8], i16[4];
#pragma unroll
  for (int j = 0; j < 16; ++j) i4[j] = __builtin_amdgcn_rcpf(fmaxf(c4[j], EPS));
#pragma unroll
  for (int k = 0; k < 8; ++k) i8[k] = __builtin_amdgcn_rcpf(fmaxf(c8[k], EPS));
#pragma unroll
  for (int l = 0; l < 4; ++l) i16[l] = __builtin_amdgcn_rcpf(fmaxf(c16[l], EPS));

  // ---- mask outputs (one wave per (b,tile): blockIdx.x==0), lane-select ----
  if (write_masks) {
    if (lane < 16) {
      int s = tile * 16 + lane;
      if (!GUARD || s < S4) {
        float c = 0.f;
#pragma unroll
        for (int j = 0; j < 16; ++j) c = (lane == j) ? c4[j] : c;
        out[OFF3 + (size_t)b * S4 + s] = (c > 0.f) ? 1.f : 0.f;
      }
    } else if (lane < 24) {
      int k = lane - 16, s = tile * 8 + k;
      if (!GUARD || s < S8) {
        float c = 0.f;
#pragma unroll
        for (int j = 0; j < 8; ++j) c = (k == j) ? c8[j] : c;
        out[OFF4 + (size_t)b * S8 + s] = (c > 0.f) ? 1.f : 0.f;
      }
    } else if (lane < 28) {
      int l = lane - 24, s = tile * 4 + l;
      if (!GUARD || s < S16) {
        float c = 0.f;
#pragma unroll
        for (int j = 0; j < 4; ++j) c = (l == j) ? c16[j] : c;
        out[OFF5 + (size_t)b * S16 + s] = (c > 0.f) ? 1.f : 0.f;
      }
    }
  }

  // ---- masked pair sums for this d2 column ----
  const f2* xb = x2 + (size_t)b * T * D2 + d2;
  f2 p[NP];
#pragma unroll
  for (int i = 0; i < NP; ++i) {
    int t = t0 + 2 * i;
    f2 a0 = {0.f, 0.f}, a1 = {0.f, 0.f};
    if (!GUARD || t < T) {  // t even: t<T implies t+1<T
      a0 = xb[(size_t)t * D2];
      a1 = xb[(size_t)(t + 1) * D2];
    }
    p[i] = a0 * mf[2 * i] + a1 * mf[2 * i + 1];
  }

  // ---- fused q4 build + w4 stores; keep only even q4 (needed by q8) ----
  f2* o4 = (f2*)(out + OFF0) + ((size_t)b * S4 + (size_t)tile * 16) * D2 + d2;
  f2 q4e[10];  // q4e[j] = q4[2j], j=0..9
#pragma unroll
  for (int j = 0; j < 19; ++j) {
    f2 q = p[j] + p[j + 1];
    if (j < 16) {
      if (!GUARD || (tile * 16 + j) < S4) {
        f2 v = q * i4[j];
        __builtin_nontemporal_store(v, o4 + (size_t)j * D2);
      }
    }
    if ((j & 1) == 0) q4e[j >> 1] = q;
  }

  // ---- q8 tree + w8 outputs ----
  f2 q8[9];
#pragma unroll
  for (int k = 0; k < 9; ++k) q8[k] = q4e[k] + q4e[k + 1];

  f2* o8 = (f2*)(out + OFF1) + ((size_t)b * S8 + (size_t)tile * 8) * D2 + d2;
#pragma unroll
  for (int k = 0; k < 8; ++k) {
    if (!GUARD || (tile * 8 + k) < S8) {
      f2 v = q8[k] * i8[k];
      __builtin_nontemporal_store(v, o8 + (size_t)k * D2);
    }
  }

  // ---- w16 outputs ----
  f2* o16 = (f2*)(out + OFF2) + ((size_t)b * S16 + (size_t)tile * 4) * D2 + d2;
#pragma unroll
  for (int l = 0; l < 4; ++l) {
    if (!GUARD || (tile * 4 + l) < S16) {
      f2 v = (q8[2 * l] + q8[2 * l + 2]) * i16[l];
      __builtin_nontemporal_store(v, o16 + (size_t)l * D2);
    }
  }
}

__global__ __launch_bounds__(64, 4)
void tpp_kernel(const f2* __restrict__ x2, const int* __restrict__ mask,
                float* __restrict__ out) {
  const int lane = threadIdx.x;               // 0..63
  const int d2 = blockIdx.x * 64 + lane;      // 0..255
  const int b = blockIdx.z;
  const int tile = blockIdx.y;
  const bool write_masks = (blockIdx.x == 0);

  if (tile < NTILES - 1)
    tile_body<false>(x2, mask, out, b, tile, d2, lane, write_masks);
  else
    tile_body<true>(x2, mask, out, b, tile, d2, lane, write_masks);
}

extern "C" void kernel_launch(void* const* d_in, const int* in_sizes, int n_in,
                              void* d_out, int out_size, void* d_ws,
                              size_t ws_size, hipStream_t stream) {
  const f2* x2 = (const f2*)d_in[0];
  const int* mask = (const int*)d_in[1];
  float* out = (float*)d_out;
  dim3 grid(D2 / 64, NTILES, B);  // (4,128,8) = 4096 single-wave blocks
  tpp_kernel<<<grid, 64, 0, stream>>>(x2, mask, out);
}

// Round 2
// 112.127 us; speedup vs baseline: 1.0167x; 1.0167x over previous
//
#include <hip/hip_runtime.h>

// TemporalPyramidPooling: fused overlapping masked window-means,
// (w,stride) = (4,2), (8,4), (16,8), x[8,4096,512] fp32.
// R5: revert to R3 structure (f4 lanes, 2048 single-wave blocks) — R4's f2
// occupancy attack regressed (kernel is BW-bound at ~84% achievable, not
// latency-bound; doubling waves doubled the per-wave uniform mask/count-tree
// overhead). Keep R4's one strict win: __builtin_amdgcn_rcpf for the 28
// wave-uniform window reciprocals (was 28 IEEE divide expansions).

#define EPS 1e-6f

typedef float f4 __attribute__((ext_vector_type(4)));

constexpr int B = 8, T = 4096, D = 512, D4 = D / 4;
constexpr int TILE = 32;          // window-start timesteps per block
constexpr int HALO = 8;           // w16 extends 8 past tile
constexpr int NT = TILE + HALO;   // 40 timesteps
constexpr int NP = NT / 2;        // 20 pair sums
constexpr int NTILES = T / TILE;  // 128
constexpr int S4 = 2047, S8 = 1023, S16 = 511;

constexpr size_t OFF0 = 0;                           // avg4  [B,S4,D]
constexpr size_t OFF1 = (size_t)B * S4 * D;          // avg8  [B,S8,D]
constexpr size_t OFF2 = OFF1 + (size_t)B * S8 * D;   // avg16 [B,S16,D]
constexpr size_t OFF3 = OFF2 + (size_t)B * S16 * D;  // mask4 [B,S4]
constexpr size_t OFF4 = OFF3 + (size_t)B * S4;       // mask8 [B,S8]
constexpr size_t OFF5 = OFF4 + (size_t)B * S8;       // mask16[B,S16]

template <bool GUARD>
__device__ __forceinline__ void tile_body(const f4* __restrict__ x4,
                                          const int* __restrict__ mask,
                                          float* __restrict__ out, int b,
                                          int tile, int d4, int lane,
                                          bool write_masks) {
  const int t0 = tile * TILE;

  // ---- wave-uniform mask: scalar loads + in-register float conversion ----
  const int* mp = mask + (size_t)b * T + t0;
  float mf[NT];
#pragma unroll
  for (int i = 0; i < NT; ++i) {
    int m = (!GUARD || (t0 + i) < T) ? mp[i] : 0;
    mf[i] = (m != 0) ? 1.0f : 0.0f;
  }

  // count tree (all wave-uniform)
  float c2[NP];
#pragma unroll
  for (int i = 0; i < NP; ++i) c2[i] = mf[2 * i] + mf[2 * i + 1];
  float c4[19];  // c4[j] = pairs {j,j+1}, j=0..18
#pragma unroll
  for (int j = 0; j < 19; ++j) c4[j] = c2[j] + c2[j + 1];
  float c8[9];  // c8[k] = pairs {2k..2k+3} = c4[2k]+c4[2k+2]
#pragma unroll
  for (int k = 0; k < 9; ++k) c8[k] = c4[2 * k] + c4[2 * k + 2];
  float c16[4];  // c16[l] = pairs {4l..4l+7} = c8[2l]+c8[2l+2]
#pragma unroll
  for (int l = 0; l < 4; ++l) c16[l] = c8[2 * l] + c8[2 * l + 2];

  float i4[16], i8[8], i16[4];
#pragma unroll
  for (int j = 0; j < 16; ++j) i4[j] = __builtin_amdgcn_rcpf(fmaxf(c4[j], EPS));
#pragma unroll
  for (int k = 0; k < 8; ++k) i8[k] = __builtin_amdgcn_rcpf(fmaxf(c8[k], EPS));
#pragma unroll
  for (int l = 0; l < 4; ++l) i16[l] = __builtin_amdgcn_rcpf(fmaxf(c16[l], EPS));

  // ---- mask outputs (one wave per (b,tile): blockIdx.x==0), lane-select ----
  if (write_masks) {
    if (lane < 16) {
      int s = tile * 16 + lane;
      if (!GUARD || s < S4) {
        float c = 0.f;
#pragma unroll
        for (int j = 0; j < 16; ++j) c = (lane == j) ? c4[j] : c;
        out[OFF3 + (size_t)b * S4 + s] = (c > 0.f) ? 1.f : 0.f;
      }
    } else if (lane < 24) {
      int k = lane - 16, s = tile * 8 + k;
      if (!GUARD || s < S8) {
        float c = 0.f;
#pragma unroll
        for (int j = 0; j < 8; ++j) c = (k == j) ? c8[j] : c;
        out[OFF4 + (size_t)b * S8 + s] = (c > 0.f) ? 1.f : 0.f;
      }
    } else if (lane < 28) {
      int l = lane - 24, s = tile * 4 + l;
      if (!GUARD || s < S16) {
        float c = 0.f;
#pragma unroll
        for (int j = 0; j < 4; ++j) c = (l == j) ? c16[j] : c;
        out[OFF5 + (size_t)b * S16 + s] = (c > 0.f) ? 1.f : 0.f;
      }
    }
  }

  // ---- masked pair sums for this d4 column ----
  const f4* xb = x4 + (size_t)b * T * D4 + d4;
  f4 p[NP];
#pragma unroll
  for (int i = 0; i < NP; ++i) {
    int t = t0 + 2 * i;
    f4 a0 = {0.f, 0.f, 0.f, 0.f}, a1 = {0.f, 0.f, 0.f, 0.f};
    if (!GUARD || t < T) {  // t even: t<T implies t+1<T
      a0 = xb[(size_t)t * D4];
      a1 = xb[(size_t)(t + 1) * D4];
    }
    p[i] = a0 * mf[2 * i] + a1 * mf[2 * i + 1];
  }

  // value sum tree (mirrors count tree)
  f4 q4[19];
#pragma unroll
  for (int j = 0; j < 19; ++j) q4[j] = p[j] + p[j + 1];
  f4 q8[9];
#pragma unroll
  for (int k = 0; k < 9; ++k) q8[k] = q4[2 * k] + q4[2 * k + 2];

  // w=4 outputs
  f4* o4 = (f4*)(out + OFF0) + ((size_t)b * S4 + (size_t)tile * 16) * D4 + d4;
#pragma unroll
  for (int j = 0; j < 16; ++j) {
    if (!GUARD || (tile * 16 + j) < S4) {
      f4 v = q4[j] * i4[j];
      __builtin_nontemporal_store(v, o4 + (size_t)j * D4);
    }
  }

  // w=8 outputs
  f4* o8 = (f4*)(out + OFF1) + ((size_t)b * S8 + (size_t)tile * 8) * D4 + d4;
#pragma unroll
  for (int k = 0; k < 8; ++k) {
    if (!GUARD || (tile * 8 + k) < S8) {
      f4 v = q8[k] * i8[k];
      __builtin_nontemporal_store(v, o8 + (size_t)k * D4);
    }
  }

  // w=16 outputs
  f4* o16 = (f4*)(out + OFF2) + ((size_t)b * S16 + (size_t)tile * 4) * D4 + d4;
#pragma unroll
  for (int l = 0; l < 4; ++l) {
    if (!GUARD || (tile * 4 + l) < S16) {
      f4 v = (q8[2 * l] + q8[2 * l + 2]) * i16[l];
      __builtin_nontemporal_store(v, o16 + (size_t)l * D4);
    }
  }
}

__global__ __launch_bounds__(64)
void tpp_kernel(const f4* __restrict__ x4, const int* __restrict__ mask,
                float* __restrict__ out) {
  const int lane = threadIdx.x;               // 0..63
  const int d4 = blockIdx.x * 64 + lane;      // 0..127
  const int b = blockIdx.z;
  const int tile = blockIdx.y;
  const bool write_masks = (blockIdx.x == 0);

  if (tile < NTILES - 1)
    tile_body<false>(x4, mask, out, b, tile, d4, lane, write_masks);
  else
    tile_body<true>(x4, mask, out, b, tile, d4, lane, write_masks);
}

extern "C" void kernel_launch(void* const* d_in, const int* in_sizes, int n_in,
                              void* d_out, int out_size, void* d_ws,
                              size_t ws_size, hipStream_t stream) {
  const f4* x4 = (const f4*)d_in[0];
  const int* mask = (const int*)d_in[1];
  float* out = (float*)d_out;
  dim3 grid(D4 / 64, NTILES, B);  // (2,128,8) = 2048 single-wave blocks
  tpp_kernel<<<grid, 64, 0, stream>>>(x4, mask, out);
}